// Round 14
// baseline (105.924 us; speedup 1.0000x reference)
//
#include <hip/hip_runtime.h>
#include <stdint.h>
#include <math.h>

#define EPS 1e-5f
// B=32, N=4096, C=96, H=192

typedef __attribute__((ext_vector_type(8))) short bf16x8;
typedef __attribute__((ext_vector_type(4))) float f32x4;
typedef __attribute__((ext_vector_type(2))) float f32x2;   // packed-math complex

__device__ __forceinline__ unsigned short f2bf(float f) {
    unsigned u = __float_as_uint(f);
    unsigned r = (u + 0x7FFFu + ((u >> 16) & 1u)) >> 16;
    return (unsigned short)r;
}
__device__ __forceinline__ float bf2f(unsigned short h) {
    return __uint_as_float(((unsigned)h) << 16);
}

__device__ __forceinline__ f32x2 mk2(float x, float y) { f32x2 r; r.x = x; r.y = y; return r; }
__device__ __forceinline__ f32x2 irot(f32x2 a) { return mk2(-a.y, a.x); }
// a * (c + i s), c/s scalar
__device__ __forceinline__ f32x2 cmulk(f32x2 a, float c, float s) {
    f32x2 as = mk2(-a.y, a.x);
    return a * mk2(c, c) + as * mk2(s, s);
}
// a * b
__device__ __forceinline__ f32x2 cmulv(f32x2 a, f32x2 b) {
    f32x2 as = mk2(-a.y, a.x);
    return a * mk2(b.x, b.x) + as * mk2(b.y, b.y);
}
// a * conj(b)
__device__ __forceinline__ f32x2 cmulvc(f32x2 a, f32x2 b) {
    f32x2 as = mk2(a.y, -a.x);
    return a * mk2(b.x, b.x) + as * mk2(b.y, b.y);
}
template <int S>
__device__ __forceinline__ f32x2 cmulT(f32x2 a, f32x2 b) {
    return (S < 0) ? cmulv(a, b) : cmulvc(a, b);
}
__device__ __forceinline__ f32x2 max0(f32x2 a) {
    return mk2(fmaxf(a.x, 0.f), fmaxf(a.y, 0.f));
}

// ---------------------------------------------------------------------------
// Prep: one-time fp32 -> bf16 conversion of w1 (192x96) and w2 (96x192).
// ---------------------------------------------------------------------------
__global__ __launch_bounds__(256) void prep_w_kernel(
    const float* __restrict__ w1, const float* __restrict__ w2,
    unsigned short* __restrict__ w1b, unsigned short* __restrict__ w2b)
{
    int i = blockIdx.x * 256 + threadIdx.x;
    w1b[i] = f2bf(w1[i]);
    w2b[i] = f2bf(w2[i]);
}

// ---------------------------------------------------------------------------
// GEMM1 (MFMA): ht[b][hc][n] = bf16(relu(bn1( sum_c x[b][n][c]*w1[hc][c] )))
// m=hc(192), n=tok(128/block), K=96. grid 1024, block 256 (4 waves). PROVEN.
// ---------------------------------------------------------------------------
__global__ __launch_bounds__(256, 2) void gemm1_kernel(
    const float* __restrict__ x,              // [B*4096, 96]
    const unsigned short* __restrict__ w1b,   // [192, 96] bf16
    const float* __restrict__ g1, const float* __restrict__ be1,
    const float* __restrict__ mu1, const float* __restrict__ va1,
    unsigned short* __restrict__ ht)          // [B,192,4096] bf16
{
    __shared__ unsigned short ws2[12][192][8];  // [c/8][hc][c%8]  36,864 B
    __shared__ unsigned short xs2[12][128][8];  // [c/8][tok][c%8] 24,576 B
    __shared__ float sb[2][192];                //                  1,536 B

    const int tid = threadIdx.x;
    const int T0 = blockIdx.x * 128;
    const int b  = T0 >> 12;
    const int n0 = T0 & 4095;
    const int lane = tid & 63, wid = tid >> 6;
    const int lm = lane & 15, lg = lane >> 4;

    if (tid < 192) {
        float s = g1[tid] * rsqrtf(va1[tid] + EPS);
        sb[0][tid] = s;
        sb[1][tid] = be1[tid] - mu1[tid] * s;
    }
    #pragma unroll
    for (int i = 0; i < 9; ++i) {
        int id = tid + i * 256;
        int ch = id / 12, c8 = (id % 12) * 8;
        *(uint4*)&ws2[c8 >> 3][ch][0] = *(const uint4*)(w1b + (size_t)ch * 96 + c8);
    }
    const float* xb = x + (size_t)T0 * 96;
    #pragma unroll
    for (int i = 0; i < 12; ++i) {
        int id = tid + i * 256;             // 3072 float4
        int t = id / 24, c4 = (id % 24) * 4;
        float4 v = *(const float4*)(xb + (size_t)t * 96 + c4);
        ushort4 hv = { f2bf(v.x), f2bf(v.y), f2bf(v.z), f2bf(v.w) };
        *(ushort4*)&xs2[c4 >> 3][t][c4 & 7] = hv;
    }
    __syncthreads();

    const int t0w = wid * 32;
    f32x4 acc[12][2];
    #pragma unroll
    for (int f = 0; f < 12; ++f)
        #pragma unroll
        for (int nf = 0; nf < 2; ++nf) acc[f][nf] = (f32x4){0.f, 0.f, 0.f, 0.f};

    #pragma unroll
    for (int ks = 0; ks < 3; ++ks) {
        const int g = ks * 4 + lg;          // k-group (bijection-safe)
        bf16x8 bfrag[2];
        #pragma unroll
        for (int nf = 0; nf < 2; ++nf)
            bfrag[nf] = *(const bf16x8*)&xs2[g][t0w + nf * 16 + lm][0];
        #pragma unroll
        for (int f = 0; f < 12; ++f) {
            bf16x8 afrag = *(const bf16x8*)&ws2[g][f * 16 + lm][0];
            acc[f][0] = __builtin_amdgcn_mfma_f32_16x16x32_bf16(afrag, bfrag[0], acc[f][0], 0, 0, 0);
            acc[f][1] = __builtin_amdgcn_mfma_f32_16x16x32_bf16(afrag, bfrag[1], acc[f][1], 0, 0, 0);
        }
    }

    unsigned short* hb = ht + (size_t)b * 192 * 4096 + n0;
    #pragma unroll
    for (int f = 0; f < 12; ++f) {
        #pragma unroll
        for (int r = 0; r < 4; ++r) {
            int hc = f * 16 + lg * 4 + r;
            float s = sb[0][hc], bb = sb[1][hc];
            #pragma unroll
            for (int nf = 0; nf < 2; ++nf) {
                float v = fmaxf(fmaf(acc[f][nf][r], s, bb), 0.f);
                hb[(size_t)hc * 4096 + t0w + nf * 16 + lm] = f2bf(v);
            }
        }
    }
}

// ---------------------------------------------------------------------------
// Radix-16 register FFT, packed-fp32, single 32 KB fp32 buffer (R10-proven).
// Twiddles WA/WB computed ONCE per thread (forward sign) and reused for the
// inverse via multiply-by-conjugate — removes 2 sincos + 2 ladders/thread.
// ---------------------------------------------------------------------------
#define NBIDX(k) ((((k) & 0x0FF0)) | (((k) ^ ((k) >> 4)) & 0x0F))

template <int S>
__device__ __forceinline__ void dft16(f32x2 v[16]) {
    const float C1 = 0.92387953251128675613f;
    const float S1 = 0.38268343236508977173f;
    const float R  = 0.70710678118654752440f;
    const float sg = (float)S;
    f32x2 g[16];
    #pragma unroll
    for (int a1 = 0; a1 < 4; ++a1) {
        f32x2 v0 = v[a1], v1 = v[a1 + 4], v2 = v[a1 + 8], v3 = v[a1 + 12];
        f32x2 t0 = v0 + v2, t1 = v0 - v2;
        f32x2 t2 = v1 + v3, t3 = v1 - v3;
        f32x2 u = irot(t3);
        g[0 * 4 + a1] = t0 + t2;
        g[1 * 4 + a1] = (S > 0) ? (t1 + u) : (t1 - u);
        g[2 * 4 + a1] = t0 - t2;
        g[3 * 4 + a1] = (S > 0) ? (t1 - u) : (t1 + u);
    }
    g[4 + 1]  = cmulk(g[4 + 1],  C1,  sg * S1);
    g[4 + 2]  = cmulk(g[4 + 2],  R,   sg * R);
    g[4 + 3]  = cmulk(g[4 + 3],  S1,  sg * C1);
    g[8 + 1]  = cmulk(g[8 + 1],  R,   sg * R);
    {
        f32x2 a = g[8 + 2];
        g[8 + 2] = (S > 0) ? irot(a) : mk2(a.y, -a.x);
    }
    g[8 + 3]  = cmulk(g[8 + 3],  -R,  sg * R);
    g[12 + 1] = cmulk(g[12 + 1], S1,  sg * C1);
    g[12 + 2] = cmulk(g[12 + 2], -R,  sg * R);
    g[12 + 3] = cmulk(g[12 + 3], -C1, -sg * S1);
    #pragma unroll
    for (int r1 = 0; r1 < 4; ++r1) {
        f32x2 v0 = g[r1 * 4 + 0], v1 = g[r1 * 4 + 1],
              v2 = g[r1 * 4 + 2], v3 = g[r1 * 4 + 3];
        f32x2 t0 = v0 + v2, t1 = v0 - v2;
        f32x2 t2 = v1 + v3, t3 = v1 - v3;
        f32x2 u = irot(t3);
        v[r1 + 0]  = t0 + t2;
        v[r1 + 4]  = (S > 0) ? (t1 + u) : (t1 - u);
        v[r1 + 8]  = t0 - t2;
        v[r1 + 12] = (S > 0) ? (t1 - u) : (t1 + u);
    }
}

__device__ __forceinline__ void twiddle_ladder(f32x2 w, f32x2 W[16]) {
    W[1] = w;
    W[2] = cmulv(W[1], W[1]);
    W[3] = cmulv(W[2], W[1]);
    W[4] = cmulv(W[2], W[2]);
    W[5] = cmulv(W[4], W[1]);
    W[6] = cmulv(W[4], W[2]);
    W[7] = cmulv(W[4], W[3]);
    W[8] = cmulv(W[4], W[4]);
    #pragma unroll
    for (int j = 1; j < 8; ++j) W[8 + j] = cmulv(W[8], W[j]);
}

template <int S>
__device__ __forceinline__ void fft4096_ip(f32x2* __restrict__ SB, int tid,
                                           const f32x2 WA[16], const f32x2 WB[16])
{
    f32x2 v[16];
    // ---- pass A: wave w reads/writes columns [64w,64w+63] only ----
    {
        const int ii = (tid & 0xF0) | ((tid ^ (tid >> 4)) & 0x0F);
        #pragma unroll
        for (int a = 0; a < 16; ++a) v[a] = SB[a * 256 + ii];
        dft16<S>(v);
        #pragma unroll
        for (int r2 = 1; r2 < 16; ++r2) v[r2] = cmulT<S>(v[r2], WA[r2]);
        __builtin_amdgcn_sched_barrier(0);   // intra-wave read->write order
        #pragma unroll
        for (int r2 = 0; r2 < 16; ++r2) SB[r2 * 256 + tid] = v[r2];
    }
    __syncthreads();                          // cross-wave: A-writes -> B-reads
    const int r = tid >> 4, t1 = tid & 15;
    // ---- pass B: row r is owned by 16 consecutive lanes (one wave) ----
    {
        #pragma unroll
        for (int t2 = 0; t2 < 16; ++t2) v[t2] = SB[r * 256 + t2 * 16 + t1];
        dft16<S>(v);
        #pragma unroll
        for (int m = 1; m < 16; ++m) v[m] = cmulT<S>(v[m], WB[m]);
        __builtin_amdgcn_sched_barrier(0);   // intra-wave read->write order
        #pragma unroll
        for (int m = 0; m < 16; ++m) SB[r * 256 + m * 16 + (t1 ^ m)] = v[m];
    }
    __builtin_amdgcn_sched_barrier(0);        // B->C same-row, same lanes
    // ---- pass C ----
    {
        const int m = tid & 15;
        #pragma unroll
        for (int q = 0; q < 16; ++q) v[q] = SB[r * 256 + m * 16 + (q ^ m)];
        dft16<S>(v);
        const int inner = (m * 16) | ((r ^ m) & 15);
        __syncthreads();                      // cross-wave: all C-reads done
        #pragma unroll
        for (int p = 0; p < 16; ++p) SB[p * 256 + inner] = v[p];
    }
    __syncthreads();                          // cross-wave: C-writes visible
}

// ---------------------------------------------------------------------------
// FFT middle kernel, bf16 I/O, 32 KB LDS. grid (96, 32), block 256.
// No min-waves bound (R6 lesson: forcing VGPR down spills).
// ---------------------------------------------------------------------------
__global__ __launch_bounds__(256) void fft_mid_kernel(
    unsigned short* __restrict__ ht,   // [B,192,4096] bf16 in/out
    const float* __restrict__ rmat,
    const float* __restrict__ imat,
    const float* __restrict__ rb,
    const float* __restrict__ ib)
{
    __shared__ f32x2 SB[4096];   // 32,768 B

    const int tid = threadIdx.x;
    const int pp  = blockIdx.x;
    const int b   = blockIdx.y;
    const int h1  = 2 * pp, h2 = 2 * pp + 1;
    unsigned short* row1 = ht + ((size_t)b * 192 + h1) * 4096;
    unsigned short* row2 = ht + ((size_t)b * 192 + h2) * 4096;

    #pragma unroll
    for (int i = 0; i < 2; ++i) {
        int nb = i * 2048 + tid * 8;
        uint4 v1 = *(const uint4*)(row1 + nb);
        uint4 v2 = *(const uint4*)(row2 + nb);
        const unsigned short* p1 = (const unsigned short*)&v1;
        const unsigned short* p2 = (const unsigned short*)&v2;
        int a = nb >> 8;
        #pragma unroll
        for (int j = 0; j < 8; ++j) {
            int t = (nb + j) & 255;
            int ii = (t & 0xF0) | ((t ^ (t >> 4)) & 0x0F);
            SB[a * 256 + ii] = mk2(bf2f(p1[j]), bf2f(p2[j]));
        }
    }

    // twiddles computed once (forward sign), reused conjugated for inverse
    const float TWO_PI = 6.28318530717958647692f;
    f32x2 WA[16], WB[16];
    {
        float c0, s0;
        __sincosf(-TWO_PI * (float)tid * (1.f / 4096.f), &s0, &c0);
        twiddle_ladder(mk2(c0, s0), WA);
        __sincosf(-TWO_PI * (float)(tid & 15) * (1.f / 256.f), &s0, &c0);
        twiddle_ladder(mk2(c0, s0), WB);
    }
    __syncthreads();

    fft4096_ip<-1>(SB, tid, WA, WB);

    const f32x2 RD = mk2(rmat[(size_t)h1 * 192 + h1], rmat[(size_t)h2 * 192 + h2]);
    const f32x2 IG = mk2(imat[(size_t)h1 * 192 + h1], imat[(size_t)h2 * 192 + h2]);
    const f32x2 RB = mk2(rb[h1], rb[h2]);
    const f32x2 IB = mk2(ib[h1], ib[h2]);

    // in-place mix: each k in [0,2048] owned by exactly one thread.
    for (int k = tid; k <= 2048; k += 256) {
        int m = (4096 - k) & 4095;
        f32x2 Fk = SB[NBIDX(k)], Fm = SB[NBIDX(m)];
        const float sc = 1.f / 128.f;   // 0.5 (unpack) * 1/64 (ortho fwd)
        f32x2 P = mk2(Fk.x + Fm.x, Fk.y + Fm.y) * mk2(sc, sc);
        f32x2 Q = mk2(Fk.y - Fm.y, Fm.x - Fk.x) * mk2(sc, sc);
        f32x2 Zkr = max0(P * RD - Q * IG + RB);
        f32x2 Zki = max0(Q * RD + P * IG + IB);
        f32x2 Zmr = max0(P * RD + Q * IG + RB);
        f32x2 Zmi = max0(P * IG - Q * RD + IB);
        float A = Zkr.x + Zmr.x, Bv = Zki.y - Zmi.y;
        float C = Zki.x - Zmi.x, D = Zkr.y + Zmr.y;
        SB[NBIDX(k)] = mk2(0.5f * (A - Bv), 0.5f * (C + D));
        SB[NBIDX(m)] = mk2(0.5f * (A + Bv), 0.5f * (D - C));
    }
    __syncthreads();

    fft4096_ip<1>(SB, tid, WA, WB);

    const float inv = 1.f / 64.f;
    #pragma unroll
    for (int i = 0; i < 2; ++i) {
        int nb = i * 2048 + tid * 8;
        uint4 v1, v2;
        unsigned short* p1 = (unsigned short*)&v1;
        unsigned short* p2 = (unsigned short*)&v2;
        int a = nb >> 8;
        #pragma unroll
        for (int j = 0; j < 8; ++j) {
            int t = (nb + j) & 255;
            int ii = (t & 0xF0) | ((t ^ (t >> 4)) & 0x0F);
            f32x2 g = SB[a * 256 + ii];
            p1[j] = f2bf(g.x * inv);
            p2[j] = f2bf(g.y * inv);
        }
        *(uint4*)(row1 + nb) = v1;
        *(uint4*)(row2 + nb) = v2;
    }
}

// ---------------------------------------------------------------------------
// GEMM2 (MFMA, fused transpose): out[t][c] = bn2( sum_hc ht[b][hc][t]*w2[c][hc] )
// Per block: 64 tokens x 96 ch, K=192. grid 2048, block 256.
// Packed hc-pair uint staging (R9-proven).
// ---------------------------------------------------------------------------
__global__ __launch_bounds__(256, 2) void gemm2_kernel(
    const unsigned short* __restrict__ ht,    // [B,192,4096] bf16
    const unsigned short* __restrict__ w2b,   // [96,192] bf16
    const float* __restrict__ g2, const float* __restrict__ be2,
    const float* __restrict__ mu2, const float* __restrict__ va2,
    float* __restrict__ out)                  // [B*4096, 96]
{
    __shared__ unsigned short at[64][208];    // [tok][hc] pad->416B rows, 26,624 B
    __shared__ unsigned short w2s[96][200];   // [ch][K]   pad->400B rows, 38,400 B

    const int tid = threadIdx.x;
    const int T0 = blockIdx.x * 64;
    const int b  = T0 >> 12;
    const int n0 = T0 & 4095;
    const int lane = tid & 63, wid = tid >> 6;
    const int lm = lane & 15, lg = lane >> 4;

    #pragma unroll
    for (int i = 0; i < 9; ++i) {
        int id = tid + i * 256;
        int ch = id / 24, k8 = (id % 24) * 8;
        *(uint4*)&w2s[ch][k8] = *(const uint4*)(w2b + (size_t)ch * 192 + k8);
    }
    const unsigned short* src = ht + (size_t)b * 192 * 4096 + n0;
    #pragma unroll
    for (int i = 0; i < 3; ++i) {
        int pid = tid + i * 256;             // 0..767
        int hc0 = (pid >> 3) * 2, t8 = (pid & 7) * 8;
        uint4 v0 = *(const uint4*)(src + (size_t)hc0 * 4096 + t8);
        uint4 v1 = *(const uint4*)(src + (size_t)(hc0 + 1) * 4096 + t8);
        const unsigned short* p0 = (const unsigned short*)&v0;
        const unsigned short* p1 = (const unsigned short*)&v1;
        #pragma unroll
        for (int u = 0; u < 8; ++u) {
            *(unsigned*)&at[t8 + u][hc0] = (unsigned)p0[u] | ((unsigned)p1[u] << 16);
        }
    }
    __syncthreads();

    f32x4 acc[6];
    #pragma unroll
    for (int nf = 0; nf < 6; ++nf) acc[nf] = (f32x4){0.f, 0.f, 0.f, 0.f};

    #pragma unroll
    for (int ks = 0; ks < 6; ++ks) {
        const int k0 = ks * 32 + lg * 8;
        bf16x8 afrag = *(const bf16x8*)&at[wid * 16 + lm][k0];
        #pragma unroll
        for (int nf = 0; nf < 6; ++nf) {
            bf16x8 bfv = *(const bf16x8*)&w2s[nf * 16 + lm][k0];
            acc[nf] = __builtin_amdgcn_mfma_f32_16x16x32_bf16(afrag, bfv, acc[nf], 0, 0, 0);
        }
    }

    // epilogue: lane holds C[tok = wid*16 + lg*4 + r][ch = nf*16 + lm]
    float* ob = out + (size_t)T0 * 96;
    #pragma unroll
    for (int nf = 0; nf < 6; ++nf) {
        int ch = nf * 16 + lm;
        float s  = g2[ch] * rsqrtf(va2[ch] + EPS);
        float bb = be2[ch] - mu2[ch] * s;
        int tokb = wid * 16 + lg * 4;
        #pragma unroll
        for (int r = 0; r < 4; ++r) {
            ob[(size_t)(tokb + r) * 96 + ch] = fmaf(acc[nf][r], s, bb);
        }
    }
}

// ---------------------------------------------------------------------------
extern "C" void kernel_launch(void* const* d_in, const int* in_sizes, int n_in,
                              void* d_out, int out_size, void* d_ws, size_t ws_size,
                              hipStream_t stream)
{
    const float* x   = (const float*)d_in[0];
    const float* w1  = (const float*)d_in[1];
    const float* g1  = (const float*)d_in[2];
    const float* be1 = (const float*)d_in[3];
    const float* mu1 = (const float*)d_in[4];
    const float* va1 = (const float*)d_in[5];
    const float* r   = (const float*)d_in[6];
    const float* im  = (const float*)d_in[7];
    const float* rb  = (const float*)d_in[8];
    const float* ib  = (const float*)d_in[9];
    const float* w2  = (const float*)d_in[10];
    const float* g2  = (const float*)d_in[11];
    const float* be2 = (const float*)d_in[12];
    const float* mu2 = (const float*)d_in[13];
    const float* va2 = (const float*)d_in[14];
    float* out = (float*)d_out;

    unsigned short* ht  = (unsigned short*)d_ws;             // 50,331,648 B
    unsigned short* w1b = ht + (size_t)32 * 192 * 4096;      // 36,864 B
    unsigned short* w2b = w1b + 192 * 96;                    // 36,864 B

    prep_w_kernel<<<dim3(72), 256, 0, stream>>>(w1, w2, w1b, w2b);
    gemm1_kernel<<<dim3(1024), 256, 0, stream>>>(x, w1b, g1, be1, mu1, va1, ht);
    fft_mid_kernel<<<dim3(96, 32), 256, 0, stream>>>(ht, r, im, rb, ib);
    gemm2_kernel<<<dim3(2048), 256, 0, stream>>>(ht, w2b, g2, be2, mu2, va2, out);
}

// Round 15
// 96.145 us; speedup vs baseline: 1.1017x; 1.1017x over previous
//
#include <hip/hip_runtime.h>
#include <stdint.h>
#include <math.h>

#define EPS 1e-5f
// B=32, N=4096, C=96, H=192

typedef __attribute__((ext_vector_type(8))) short bf16x8;
typedef __attribute__((ext_vector_type(4))) float f32x4;
typedef __attribute__((ext_vector_type(2))) float f32x2;   // packed-math complex

__device__ __forceinline__ unsigned short f2bf(float f) {
    unsigned u = __float_as_uint(f);
    unsigned r = (u + 0x7FFFu + ((u >> 16) & 1u)) >> 16;
    return (unsigned short)r;
}
__device__ __forceinline__ float bf2f(unsigned short h) {
    return __uint_as_float(((unsigned)h) << 16);
}

__device__ __forceinline__ f32x2 mk2(float x, float y) { f32x2 r; r.x = x; r.y = y; return r; }
__device__ __forceinline__ f32x2 irot(f32x2 a) { return mk2(-a.y, a.x); }
// a * (c + i s), c/s scalar
__device__ __forceinline__ f32x2 cmulk(f32x2 a, float c, float s) {
    f32x2 as = mk2(-a.y, a.x);
    return a * mk2(c, c) + as * mk2(s, s);
}
// a * b
__device__ __forceinline__ f32x2 cmulv(f32x2 a, f32x2 b) {
    f32x2 as = mk2(-a.y, a.x);
    return a * mk2(b.x, b.x) + as * mk2(b.y, b.y);
}
__device__ __forceinline__ f32x2 max0(f32x2 a) {
    return mk2(fmaxf(a.x, 0.f), fmaxf(a.y, 0.f));
}

// ---------------------------------------------------------------------------
// GEMM1 (MFMA): ht[b][hc][n] = bf16(relu(bn1( sum_c x[b][n][c]*w1[hc][c] )))
// m=hc(192), n=tok(128/block), K=96. grid 1024, block 256 (4 waves). PROVEN.
// w1 converted fp32->bf16 during staging (w1 is L2-resident; no prep pass).
// ---------------------------------------------------------------------------
__global__ __launch_bounds__(256, 2) void gemm1_kernel(
    const float* __restrict__ x,    // [B*4096, 96]
    const float* __restrict__ w1,   // [192, 96]
    const float* __restrict__ g1, const float* __restrict__ be1,
    const float* __restrict__ mu1, const float* __restrict__ va1,
    unsigned short* __restrict__ ht)  // [B,192,4096] bf16
{
    __shared__ unsigned short ws2[12][192][8];  // [c/8][hc][c%8]  36,864 B
    __shared__ unsigned short xs2[12][128][8];  // [c/8][tok][c%8] 24,576 B
    __shared__ float sb[2][192];                //                  1,536 B

    const int tid = threadIdx.x;
    const int T0 = blockIdx.x * 128;
    const int b  = T0 >> 12;
    const int n0 = T0 & 4095;
    const int lane = tid & 63, wid = tid >> 6;
    const int lm = lane & 15, lg = lane >> 4;

    if (tid < 192) {
        float s = g1[tid] * rsqrtf(va1[tid] + EPS);
        sb[0][tid] = s;
        sb[1][tid] = be1[tid] - mu1[tid] * s;
    }
    // stage w1 -> bf16 subtiled (4608 float4)
    #pragma unroll
    for (int i = 0; i < 18; ++i) {
        int id = tid + i * 256;
        int ch = id / 24, c4 = (id % 24) * 4;
        float4 v = *(const float4*)(w1 + (size_t)ch * 96 + c4);
        ushort4 hv = { f2bf(v.x), f2bf(v.y), f2bf(v.z), f2bf(v.w) };
        *(ushort4*)&ws2[c4 >> 3][ch][c4 & 7] = hv;
    }
    const float* xb = x + (size_t)T0 * 96;
    #pragma unroll
    for (int i = 0; i < 12; ++i) {
        int id = tid + i * 256;             // 3072 float4
        int t = id / 24, c4 = (id % 24) * 4;
        float4 v = *(const float4*)(xb + (size_t)t * 96 + c4);
        ushort4 hv = { f2bf(v.x), f2bf(v.y), f2bf(v.z), f2bf(v.w) };
        *(ushort4*)&xs2[c4 >> 3][t][c4 & 7] = hv;
    }
    __syncthreads();

    const int t0w = wid * 32;
    f32x4 acc[12][2];
    #pragma unroll
    for (int f = 0; f < 12; ++f)
        #pragma unroll
        for (int nf = 0; nf < 2; ++nf) acc[f][nf] = (f32x4){0.f, 0.f, 0.f, 0.f};

    #pragma unroll
    for (int ks = 0; ks < 3; ++ks) {
        const int g = ks * 4 + lg;          // k-group (bijection-safe)
        bf16x8 bfrag[2];
        #pragma unroll
        for (int nf = 0; nf < 2; ++nf)
            bfrag[nf] = *(const bf16x8*)&xs2[g][t0w + nf * 16 + lm][0];
        #pragma unroll
        for (int f = 0; f < 12; ++f) {
            bf16x8 afrag = *(const bf16x8*)&ws2[g][f * 16 + lm][0];
            acc[f][0] = __builtin_amdgcn_mfma_f32_16x16x32_bf16(afrag, bfrag[0], acc[f][0], 0, 0, 0);
            acc[f][1] = __builtin_amdgcn_mfma_f32_16x16x32_bf16(afrag, bfrag[1], acc[f][1], 0, 0, 0);
        }
    }

    unsigned short* hb = ht + (size_t)b * 192 * 4096 + n0;
    #pragma unroll
    for (int f = 0; f < 12; ++f) {
        #pragma unroll
        for (int r = 0; r < 4; ++r) {
            int hc = f * 16 + lg * 4 + r;
            float s = sb[0][hc], bb = sb[1][hc];
            #pragma unroll
            for (int nf = 0; nf < 2; ++nf) {
                float v = fmaxf(fmaf(acc[f][nf][r], s, bb), 0.f);
                hb[(size_t)hc * 4096 + t0w + nf * 16 + lm] = f2bf(v);
            }
        }
    }
}

// ---------------------------------------------------------------------------
// Radix-16 register FFT, packed-fp32, sincos+ladder twiddles (champion
// config: 64 VGPR, 32 KB fp32 LDS — R9/R13/R14 showed tables, fp16-LDS,
// and reg-cached twiddles all lose to this equilibrium).
// ---------------------------------------------------------------------------
#define NBIDX(k) ((((k) & 0x0FF0)) | (((k) ^ ((k) >> 4)) & 0x0F))

template <int S>
__device__ __forceinline__ void dft16(f32x2 v[16]) {
    const float C1 = 0.92387953251128675613f;
    const float S1 = 0.38268343236508977173f;
    const float R  = 0.70710678118654752440f;
    const float sg = (float)S;
    f32x2 g[16];
    #pragma unroll
    for (int a1 = 0; a1 < 4; ++a1) {
        f32x2 v0 = v[a1], v1 = v[a1 + 4], v2 = v[a1 + 8], v3 = v[a1 + 12];
        f32x2 t0 = v0 + v2, t1 = v0 - v2;
        f32x2 t2 = v1 + v3, t3 = v1 - v3;
        f32x2 u = irot(t3);
        g[0 * 4 + a1] = t0 + t2;
        g[1 * 4 + a1] = (S > 0) ? (t1 + u) : (t1 - u);
        g[2 * 4 + a1] = t0 - t2;
        g[3 * 4 + a1] = (S > 0) ? (t1 - u) : (t1 + u);
    }
    g[4 + 1]  = cmulk(g[4 + 1],  C1,  sg * S1);
    g[4 + 2]  = cmulk(g[4 + 2],  R,   sg * R);
    g[4 + 3]  = cmulk(g[4 + 3],  S1,  sg * C1);
    g[8 + 1]  = cmulk(g[8 + 1],  R,   sg * R);
    {
        f32x2 a = g[8 + 2];
        g[8 + 2] = (S > 0) ? irot(a) : mk2(a.y, -a.x);
    }
    g[8 + 3]  = cmulk(g[8 + 3],  -R,  sg * R);
    g[12 + 1] = cmulk(g[12 + 1], S1,  sg * C1);
    g[12 + 2] = cmulk(g[12 + 2], -R,  sg * R);
    g[12 + 3] = cmulk(g[12 + 3], -C1, -sg * S1);
    #pragma unroll
    for (int r1 = 0; r1 < 4; ++r1) {
        f32x2 v0 = g[r1 * 4 + 0], v1 = g[r1 * 4 + 1],
              v2 = g[r1 * 4 + 2], v3 = g[r1 * 4 + 3];
        f32x2 t0 = v0 + v2, t1 = v0 - v2;
        f32x2 t2 = v1 + v3, t3 = v1 - v3;
        f32x2 u = irot(t3);
        v[r1 + 0]  = t0 + t2;
        v[r1 + 4]  = (S > 0) ? (t1 + u) : (t1 - u);
        v[r1 + 8]  = t0 - t2;
        v[r1 + 12] = (S > 0) ? (t1 - u) : (t1 + u);
    }
}

__device__ __forceinline__ void twiddle_ladder(f32x2 w, f32x2 W[16]) {
    W[1] = w;
    W[2] = cmulv(W[1], W[1]);
    W[3] = cmulv(W[2], W[1]);
    W[4] = cmulv(W[2], W[2]);
    W[5] = cmulv(W[4], W[1]);
    W[6] = cmulv(W[4], W[2]);
    W[7] = cmulv(W[4], W[3]);
    W[8] = cmulv(W[4], W[4]);
    #pragma unroll
    for (int j = 1; j < 8; ++j) W[8 + j] = cmulv(W[8], W[j]);
}

template <int S>
__device__ __forceinline__ void fft4096_ip(f32x2* __restrict__ SB, int tid)
{
    const float TWO_PI = 6.28318530717958647692f;
    f32x2 v[16];
    // ---- pass A: wave w reads/writes columns [64w,64w+63] only ----
    {
        const int ii = (tid & 0xF0) | ((tid ^ (tid >> 4)) & 0x0F);
        #pragma unroll
        for (int a = 0; a < 16; ++a) v[a] = SB[a * 256 + ii];
        dft16<S>(v);
        float c0, s0;
        __sincosf((float)S * TWO_PI * (float)tid * (1.f / 4096.f), &s0, &c0);
        f32x2 W[16];
        twiddle_ladder(mk2(c0, s0), W);
        #pragma unroll
        for (int r2 = 1; r2 < 16; ++r2) v[r2] = cmulv(v[r2], W[r2]);
        __builtin_amdgcn_sched_barrier(0);   // intra-wave read->write order
        #pragma unroll
        for (int r2 = 0; r2 < 16; ++r2) SB[r2 * 256 + tid] = v[r2];
    }
    __syncthreads();                          // cross-wave: A-writes -> B-reads
    const int r = tid >> 4, t1 = tid & 15;
    // ---- pass B: row r is owned by 16 consecutive lanes (one wave) ----
    {
        #pragma unroll
        for (int t2 = 0; t2 < 16; ++t2) v[t2] = SB[r * 256 + t2 * 16 + t1];
        dft16<S>(v);
        float c0, s0;
        __sincosf((float)S * TWO_PI * (float)t1 * (1.f / 256.f), &s0, &c0);
        f32x2 W[16];
        twiddle_ladder(mk2(c0, s0), W);
        #pragma unroll
        for (int m = 1; m < 16; ++m) v[m] = cmulv(v[m], W[m]);
        __builtin_amdgcn_sched_barrier(0);   // intra-wave read->write order
        #pragma unroll
        for (int m = 0; m < 16; ++m) SB[r * 256 + m * 16 + (t1 ^ m)] = v[m];
    }
    __builtin_amdgcn_sched_barrier(0);        // B->C same-row, same lanes
    // ---- pass C ----
    {
        const int m = tid & 15;
        #pragma unroll
        for (int q = 0; q < 16; ++q) v[q] = SB[r * 256 + m * 16 + (q ^ m)];
        dft16<S>(v);
        const int inner = (m * 16) | ((r ^ m) & 15);
        __syncthreads();                      // cross-wave: all C-reads done
        #pragma unroll
        for (int p = 0; p < 16; ++p) SB[p * 256 + inner] = v[p];
    }
    __syncthreads();                          // cross-wave: C-writes visible
}

// ---------------------------------------------------------------------------
// FFT middle kernel, bf16 I/O, 32 KB LDS. grid (96, 32), block 256.
// Inverse-ortho 1/64 folded into the mix's 0.5 constants (pure linear
// scale applied post-ReLU -> exact); store phase is convert-only.
// No min-waves bound (R6 lesson: forcing VGPR down spills).
// ---------------------------------------------------------------------------
__global__ __launch_bounds__(256) void fft_mid_kernel(
    unsigned short* __restrict__ ht,   // [B,192,4096] bf16 in/out
    const float* __restrict__ rmat,
    const float* __restrict__ imat,
    const float* __restrict__ rb,
    const float* __restrict__ ib)
{
    __shared__ f32x2 SB[4096];   // 32,768 B

    const int tid = threadIdx.x;
    const int pp  = blockIdx.x;
    const int b   = blockIdx.y;
    const int h1  = 2 * pp, h2 = 2 * pp + 1;
    unsigned short* row1 = ht + ((size_t)b * 192 + h1) * 4096;
    unsigned short* row2 = ht + ((size_t)b * 192 + h2) * 4096;

    const int t0 = (tid & 31) * 8;       // position within 256-block
    const int hsw = (t0 >> 4) & 0xF;     // swizzle key, fixed per thread
    const int swap = hsw & 1;

    #pragma unroll
    for (int i = 0; i < 2; ++i) {
        int nb = i * 2048 + tid * 8;
        int a = i * 8 + (tid >> 5);
        uint4 v1 = *(const uint4*)(row1 + nb);
        uint4 v2 = *(const uint4*)(row2 + nb);
        const unsigned short* p1 = (const unsigned short*)&v1;
        const unsigned short* p2 = (const unsigned short*)&v2;
        #pragma unroll
        for (int u = 0; u < 4; ++u) {
            int t = t0 + 2 * u;
            int iie = (t & 0xF0) | (((t ^ hsw) & 0x0F) & ~1);
            float e0 = bf2f(p1[2 * u]),     f0 = bf2f(p2[2 * u]);
            float e1 = bf2f(p1[2 * u + 1]), f1 = bf2f(p2[2 * u + 1]);
            f32x4 q;
            if (swap) q = (f32x4){e1, f1, e0, f0};
            else      q = (f32x4){e0, f0, e1, f1};
            *(f32x4*)&SB[a * 256 + iie] = q;
        }
    }
    __syncthreads();

    fft4096_ip<-1>(SB, tid);

    const f32x2 RD = mk2(rmat[(size_t)h1 * 192 + h1], rmat[(size_t)h2 * 192 + h2]);
    const f32x2 IG = mk2(imat[(size_t)h1 * 192 + h1], imat[(size_t)h2 * 192 + h2]);
    const f32x2 RB = mk2(rb[h1], rb[h2]);
    const f32x2 IB = mk2(ib[h1], ib[h2]);

    // in-place mix: each k in [0,2048] owned by exactly one thread.
    // HLF = 0.5 (hermitianization) * 1/64 (inverse ortho, folded here)
    const float HLF = 0.5f / 64.f;
    for (int k = tid; k <= 2048; k += 256) {
        int m = (4096 - k) & 4095;
        f32x2 Fk = SB[NBIDX(k)], Fm = SB[NBIDX(m)];
        const float sc = 1.f / 128.f;   // 0.5 (unpack) * 1/64 (ortho fwd)
        f32x2 P = mk2(Fk.x + Fm.x, Fk.y + Fm.y) * mk2(sc, sc);
        f32x2 Q = mk2(Fk.y - Fm.y, Fm.x - Fk.x) * mk2(sc, sc);
        f32x2 Zkr = max0(P * RD - Q * IG + RB);
        f32x2 Zki = max0(Q * RD + P * IG + IB);
        f32x2 Zmr = max0(P * RD + Q * IG + RB);
        f32x2 Zmi = max0(P * IG - Q * RD + IB);
        float A = Zkr.x + Zmr.x, Bv = Zki.y - Zmi.y;
        float C = Zki.x - Zmi.x, D = Zkr.y + Zmr.y;
        SB[NBIDX(k)] = mk2(HLF * (A - Bv), HLF * (C + D));
        SB[NBIDX(m)] = mk2(HLF * (A + Bv), HLF * (D - C));
    }
    __syncthreads();

    fft4096_ip<1>(SB, tid);

    #pragma unroll
    for (int i = 0; i < 2; ++i) {
        int nb = i * 2048 + tid * 8;
        int a = i * 8 + (tid >> 5);
        uint4 v1, v2;
        unsigned short* p1 = (unsigned short*)&v1;
        unsigned short* p2 = (unsigned short*)&v2;
        #pragma unroll
        for (int u = 0; u < 4; ++u) {
            int t = t0 + 2 * u;
            int iie = (t & 0xF0) | (((t ^ hsw) & 0x0F) & ~1);
            f32x4 q = *(const f32x4*)&SB[a * 256 + iie];
            float e0, f0, e1, f1;
            if (swap) { e1 = q.x; f1 = q.y; e0 = q.z; f0 = q.w; }
            else      { e0 = q.x; f0 = q.y; e1 = q.z; f1 = q.w; }
            p1[2 * u]     = f2bf(e0);
            p1[2 * u + 1] = f2bf(e1);
            p2[2 * u]     = f2bf(f0);
            p2[2 * u + 1] = f2bf(f1);
        }
        *(uint4*)(row1 + nb) = v1;
        *(uint4*)(row2 + nb) = v2;
    }
}

// ---------------------------------------------------------------------------
// GEMM2 (MFMA, fused transpose): out[t][c] = bn2( sum_hc ht[b][hc][t]*w2[c][hc] )
// Per block: 64 tokens x 96 ch, K=192. grid 2048, block 256.
// Packed hc-pair uint staging (R9-proven). w2 converted fp32->bf16 in
// staging (L2-resident; no prep pass).
// ---------------------------------------------------------------------------
__global__ __launch_bounds__(256, 2) void gemm2_kernel(
    const unsigned short* __restrict__ ht,  // [B,192,4096] bf16
    const float* __restrict__ w2,           // [96,192]
    const float* __restrict__ g2, const float* __restrict__ be2,
    const float* __restrict__ mu2, const float* __restrict__ va2,
    float* __restrict__ out)                // [B*4096, 96]
{
    __shared__ unsigned short at[64][208];    // [tok][hc] pad->416B rows, 26,624 B
    __shared__ unsigned short w2s[96][200];   // [ch][K]   pad->400B rows, 38,400 B

    const int tid = threadIdx.x;
    const int T0 = blockIdx.x * 64;
    const int b  = T0 >> 12;
    const int n0 = T0 & 4095;
    const int lane = tid & 63, wid = tid >> 6;
    const int lm = lane & 15, lg = lane >> 4;

    // stage w2 -> bf16 (4608 float4)
    #pragma unroll
    for (int i = 0; i < 18; ++i) {
        int id = tid + i * 256;
        int ch = id / 48, k4 = (id % 48) * 4;
        float4 v = *(const float4*)(w2 + (size_t)ch * 192 + k4);
        ushort4 hv = { f2bf(v.x), f2bf(v.y), f2bf(v.z), f2bf(v.w) };
        *(ushort4*)&w2s[ch][k4] = hv;
    }
    const unsigned short* src = ht + (size_t)b * 192 * 4096 + n0;
    #pragma unroll
    for (int i = 0; i < 3; ++i) {
        int pid = tid + i * 256;             // 0..767
        int hc0 = (pid >> 3) * 2, t8 = (pid & 7) * 8;
        uint4 v0 = *(const uint4*)(src + (size_t)hc0 * 4096 + t8);
        uint4 v1 = *(const uint4*)(src + (size_t)(hc0 + 1) * 4096 + t8);
        const unsigned short* p0 = (const unsigned short*)&v0;
        const unsigned short* p1 = (const unsigned short*)&v1;
        #pragma unroll
        for (int u = 0; u < 8; ++u) {
            *(unsigned*)&at[t8 + u][hc0] = (unsigned)p0[u] | ((unsigned)p1[u] << 16);
        }
    }
    __syncthreads();

    f32x4 acc[6];
    #pragma unroll
    for (int nf = 0; nf < 6; ++nf) acc[nf] = (f32x4){0.f, 0.f, 0.f, 0.f};

    #pragma unroll
    for (int ks = 0; ks < 6; ++ks) {
        const int k0 = ks * 32 + lg * 8;
        bf16x8 afrag = *(const bf16x8*)&at[wid * 16 + lm][k0];
        #pragma unroll
        for (int nf = 0; nf < 6; ++nf) {
            bf16x8 bfv = *(const bf16x8*)&w2s[nf * 16 + lm][k0];
            acc[nf] = __builtin_amdgcn_mfma_f32_16x16x32_bf16(afrag, bfv, acc[nf], 0, 0, 0);
        }
    }

    // epilogue: lane holds C[tok = wid*16 + lg*4 + r][ch = nf*16 + lm]
    float* ob = out + (size_t)T0 * 96;
    #pragma unroll
    for (int nf = 0; nf < 6; ++nf) {
        int ch = nf * 16 + lm;
        float s  = g2[ch] * rsqrtf(va2[ch] + EPS);
        float bb = be2[ch] - mu2[ch] * s;
        int tokb = wid * 16 + lg * 4;
        #pragma unroll
        for (int r = 0; r < 4; ++r) {
            ob[(size_t)(tokb + r) * 96 + ch] = fmaf(acc[nf][r], s, bb);
        }
    }
}

// ---------------------------------------------------------------------------
extern "C" void kernel_launch(void* const* d_in, const int* in_sizes, int n_in,
                              void* d_out, int out_size, void* d_ws, size_t ws_size,
                              hipStream_t stream)
{
    const float* x   = (const float*)d_in[0];
    const float* w1  = (const float*)d_in[1];
    const float* g1  = (const float*)d_in[2];
    const float* be1 = (const float*)d_in[3];
    const float* mu1 = (const float*)d_in[4];
    const float* va1 = (const float*)d_in[5];
    const float* r   = (const float*)d_in[6];
    const float* im  = (const float*)d_in[7];
    const float* rb  = (const float*)d_in[8];
    const float* ib  = (const float*)d_in[9];
    const float* w2  = (const float*)d_in[10];
    const float* g2  = (const float*)d_in[11];
    const float* be2 = (const float*)d_in[12];
    const float* mu2 = (const float*)d_in[13];
    const float* va2 = (const float*)d_in[14];
    float* out = (float*)d_out;

    unsigned short* ht = (unsigned short*)d_ws;   // [32][192][4096] bf16 = 50.3 MB

    gemm1_kernel<<<dim3(1024), 256, 0, stream>>>(x, w1, g1, be1, mu1, va1, ht);
    fft_mid_kernel<<<dim3(96, 32), 256, 0, stream>>>(ht, r, im, rb, ib);
    gemm2_kernel<<<dim3(2048), 256, 0, stream>>>(ht, w2, g2, be2, mu2, va2, out);
}